// Round 1
// 177.003 us; speedup vs baseline: 1.1025x; 1.1025x over previous
//
#include <hip/hip_runtime.h>
#include <hip/hip_bf16.h>
#include <math.h>

// Problem constants (fixed by setup_inputs / reference)
#define B_      16
#define C_IN    64
#define FEAT_C_ 8
#define H_      112
#define W_      112
#define NH_     16      // H/7
#define NW_     16      // W/7
#define NPTS    100
#define P_      49      // 7*7
#define PLANE   (H_*W_) // 12544
#define NGRP    8       // batch pairs: g owns b = {2g, 2g+1}

// ---------------------------------------------------------------------------
// Kernel 1: deterministic partial reduction (no zero kernel, no global atomics)
//   Spart[p][n][g] = sum over b in {2g,2g+1}, nh, nw of
//                    logits[b, n, 7*nh + p_r, 7*nw + p_c]
// One block per (n, r, g): reads 2 planes x 16 rows x 112 cols, coalesced.
// Grid = 100 * 7 * 8 = 5600 blocks x 64 threads.
// ---------------------------------------------------------------------------
__global__ __launch_bounds__(64) void reduce_kernel(const float* __restrict__ logits,
                                                    float* __restrict__ Spart) {
    int blk = blockIdx.x;          // [0, 5600)
    int g   = blk & 7;             // batch-pair
    int rn  = blk >> 3;
    int r   = rn % 7;
    int n   = rn / 7;              // point index

    const float* pl0 = logits + ((size_t)(2 * g) * NPTS + n) * PLANE;
    const float* pl1 = pl0 + (size_t)NPTS * PLANE;   // b = 2g+1

    int t = threadIdx.x;           // 0..63
    float acc0 = 0.0f, acc1 = 0.0f;
    #pragma unroll
    for (int k = 0; k < 16; ++k) {
        const float* ra = pl0 + (r + 7 * k) * W_;
        const float* rb = pl1 + (r + 7 * k) * W_;
        acc0 += ra[t] + rb[t];
        if (t < 48) acc1 += ra[t + 64] + rb[t + 64];
    }

    __shared__ float bins[7];
    if (t < 7) bins[t] = 0.0f;
    __syncthreads();
    atomicAdd(&bins[t % 7], acc0);
    if (t < 48) atomicAdd(&bins[(t + 64) % 7], acc1);
    __syncthreads();

    if (t < 7) {
        // p = r*7 + c  with c = t
        Spart[(r * 7 + t) * (NPTS * NGRP) + n * NGRP + g] = bins[t];
    }
}

// ---------------------------------------------------------------------------
// Kernel 2 (FUSED weights + apply): 512 blocks x 448 threads (7 waves).
//   Phase 1a: 392 threads (49 p x 8 chunks) compute partial weighted sums
//             over the 100 points from Spart (L2/L3-resident, float4).
//   Phase 1b: 49 threads finalize params, build normalized padded 7x7 kernel
//             in LDS (static-index k5 stays in registers).
//   Phase 2 : 2401 bilinear-translate items across 448 threads -> WtT in LDS.
//   Phase 3 : wave i computes output row i for the block's 64 tiles; WtT rows
//             are read as wave-uniform float4 LDS broadcasts.
// ---------------------------------------------------------------------------
#define NTB 448

__global__ __launch_bounds__(NTB) void fused_kernel(const float* __restrict__ inp,
                                                    const float* __restrict__ Spart,
                                                    const float* __restrict__ sigx,
                                                    const float* __restrict__ sigy,
                                                    const float* __restrict__ opac,
                                                    const float* __restrict__ rho,
                                                    float* __restrict__ out) {
    __shared__ float ph1[P_][8][4];     // per-(p,chunk) partial {wsx,wsy,wop,wrho}
    __shared__ float k7n[P_][P_ + 1];   // [p][i*7+j], normalized padded kernel
    __shared__ float wopS[P_];
    __shared__ float WtT[P_ * 52];      // [q][p], row-padded to 52 (16B-aligned rows)

    int t = threadIdx.x;

    // --- phase 1a: chunk-parallel weighted sums over the 100 points ---
    if (t < 392) {
        int p = t >> 3;                 // 0..48
        int s = t & 7;                  // chunk 0..7
        int n0  = s * 12 + (s < 4 ? s : 4);   // 13,13,13,13,12,12,12,12
        int len = (s < 4) ? 13 : 12;

        float psx = 0.0f, psy = 0.0f, pop = 0.0f, prh = 0.0f;
        const float* base = Spart + p * (NPTS * NGRP);
        for (int e = 0; e < len; ++e) {
            int n = n0 + e;
            const float4* sp = (const float4*)(base + n * NGRP);
            float4 a = sp[0], b = sp[1];
            float l = (a.x + a.y + a.z + a.w + b.x + b.y + b.z + b.w)
                      * (1.0f / 4096.0f);       // mean over 16*16*16 patches
            psx += l * sigx[n];
            psy += l * sigy[n];
            pop += l * opac[n];
            prh += l * rho[n];
        }
        ph1[p][s][0] = psx; ph1[p][s][1] = psy;
        ph1[p][s][2] = pop; ph1[p][s][3] = prh;
    }
    __syncthreads();

    // --- phase 1b: finalize per-p params + normalized padded kernel ---
    if (t < P_) {
        float wsx = 0.0f, wsy = 0.0f, wop = 0.0f, wrho = 0.0f;
        #pragma unroll
        for (int s = 0; s < 8; ++s) {
            wsx  += ph1[t][s][0];
            wsy  += ph1[t][s][1];
            wop  += ph1[t][s][2];
            wrho += ph1[t][s][3];
        }
        wopS[t] = wop;

        float a   = wsx * wsx + 1e-5f;
        float d   = wsy * wsy + 1e-5f;
        float b   = wrho * wsx * wsy;
        float det = a * d - b * b;
        float ia  = d / det, ib = -b / det, idd = a / det;

        // 5x5 gaussian on linspace(-5,5,5); 1/(2*pi*sqrt(det)) cancels under
        // max-normalization.  Static indexing only -> stays in registers.
        float k5[25];
        float kmax = -1e30f;
        #pragma unroll
        for (int i = 0; i < 5; ++i) {
            float x = -5.0f + 2.5f * (float)i;
            #pragma unroll
            for (int j = 0; j < 5; ++j) {
                float y = -5.0f + 2.5f * (float)j;
                float z = -0.5f * (ia * x * x + 2.0f * ib * x * y + idd * y * y);
                float v = expf(z);
                k5[i * 5 + j] = v;
                kmax = fmaxf(kmax, v);
            }
        }
        float inv = 1.0f / kmax;

        // padded 7x7 (1-px zero border) straight into LDS
        #pragma unroll
        for (int q = 0; q < P_; ++q) k7n[t][q] = 0.0f;
        #pragma unroll
        for (int i = 0; i < 5; ++i)
            #pragma unroll
            for (int j = 0; j < 5; ++j)
                k7n[t][(i + 1) * 7 + (j + 1)] = k5[i * 5 + j] * inv;
    }
    __syncthreads();

    // --- phase 2: bilinear translate, (p,q) items -> WtT[q][p] in LDS ---
    for (int idx = t; idx < P_ * P_; idx += NTB) {
        int p = idx / P_;
        int q = idx - p * P_;
        int i = q / 7, j = q % 7;
        int r = p / 7, c = p % 7;

        float sx = 3.0f - (6.0f / 7.0f) * (float)c;   // tx*(COL-1)/2
        float sy = 3.0f - (6.0f / 7.0f) * (float)r;   // ty*(ROW-1)/2

        float ii  = (float)i + sy;
        float jj  = (float)j + sx;
        float fi0 = floorf(ii), fj0 = floorf(jj);
        int   i0  = (int)fi0,   j0  = (int)fj0;
        float wi  = ii - fi0,   wj  = jj - fj0;

        bool iv0 = (i0 >= 0)     && (i0 <= 6);
        bool iv1 = (i0 + 1 >= 0) && (i0 + 1 <= 6);
        bool jv0 = (j0 >= 0)     && (j0 <= 6);
        bool jv1 = (j0 + 1 >= 0) && (j0 + 1 <= 6);
        int ci0 = min(max(i0, 0), 6),     cj0 = min(max(j0, 0), 6);
        int ci1 = min(max(i0 + 1, 0), 6), cj1 = min(max(j0 + 1, 0), 6);

        float v00 = (iv0 && jv0) ? k7n[p][ci0 * 7 + cj0] : 0.0f;
        float v01 = (iv0 && jv1) ? k7n[p][ci0 * 7 + cj1] : 0.0f;
        float v10 = (iv1 && jv0) ? k7n[p][ci1 * 7 + cj0] : 0.0f;
        float v11 = (iv1 && jv1) ? k7n[p][ci1 * 7 + cj1] : 0.0f;

        float kt = v00 * (1.0f - wi) * (1.0f - wj)
                 + v01 * (1.0f - wi) * wj
                 + v10 * wi * (1.0f - wj)
                 + v11 * wi * wj;

        WtT[q * 52 + p] = wopS[p] * kt;
    }
    __syncthreads();

    // --- phase 3: apply.  wave i handles output row i for 64 tiles. ---
    int lane = t & 63;
    int i    = t >> 6;                       // 0..6 = output row within tile
    int bl   = blockIdx.x * 64 + lane;       // tile id [0, 32768)
    int nw = bl & 15;
    int u  = bl >> 4;
    int nh = u & 15;
    u >>= 4;
    int ch    = u & 7;
    int batch = u >> 3;

    const float* src = inp + (((size_t)batch * C_IN    + ch) * H_ + nh * 7) * W_ + nw * 7;
    float*       dst = out + (((size_t)batch * FEAT_C_ + ch) * H_ + nh * 7) * W_ + nw * 7;

    float in[P_];
    #pragma unroll
    for (int r = 0; r < 7; ++r)
        #pragma unroll
        for (int c = 0; c < 7; ++c)
            in[r * 7 + c] = src[r * W_ + c];

    #pragma unroll
    for (int j = 0; j < 7; ++j) {
        const float* w = &WtT[(i * 7 + j) * 52];   // wave-uniform LDS row, 16B-aligned
        float a0 = 0.0f, a1 = 0.0f, a2 = 0.0f, a3 = 0.0f;
        #pragma unroll
        for (int p4 = 0; p4 < 12; ++p4) {
            a0 += in[p4 * 4 + 0] * w[p4 * 4 + 0];
            a1 += in[p4 * 4 + 1] * w[p4 * 4 + 1];
            a2 += in[p4 * 4 + 2] * w[p4 * 4 + 2];
            a3 += in[p4 * 4 + 3] * w[p4 * 4 + 3];
        }
        float acc = ((a0 + a2) + (a1 + a3)) + in[48] * w[48];
        dst[i * W_ + j] = acc;
    }
}

// ---------------------------------------------------------------------------
extern "C" void kernel_launch(void* const* d_in, const int* in_sizes, int n_in,
                              void* d_out, int out_size, void* d_ws, size_t ws_size,
                              hipStream_t stream) {
    const float* inp    = (const float*)d_in[0];  // (16, 64, 112, 112)
    const float* logits = (const float*)d_in[1];  // (16, 100, 112, 112)
    const float* sigx   = (const float*)d_in[2];  // (100,)
    const float* sigy   = (const float*)d_in[3];  // (100,)
    const float* opac   = (const float*)d_in[4];  // (100,1) flat
    const float* rho    = (const float*)d_in[5];  // (100,1) flat
    // d_in[6] = scale (unused by reference)

    float* out   = (float*)d_out;                 // (16, 8, 112, 112) f32
    float* Spart = (float*)d_ws;                  // 49*100*8 floats (157 KB)

    reduce_kernel<<<NPTS * 7 * NGRP, 64, 0, stream>>>(logits, Spart);
    fused_kernel<<<(B_ * FEAT_C_ * NH_ * NW_) / 64, NTB, 0, stream>>>(
        inp, Spart, sigx, sigy, opac, rho, out);
}

// Round 2
// 172.347 us; speedup vs baseline: 1.1323x; 1.0270x over previous
//
#include <hip/hip_runtime.h>
#include <hip/hip_bf16.h>
#include <math.h>

// Problem constants (fixed by setup_inputs / reference)
#define B_      16
#define C_IN    64
#define FEAT_C_ 8
#define H_      112
#define W_      112
#define NH_     16      // H/7
#define NW_     16      // W/7
#define NPTS    100
#define P_      49      // 7*7
#define PLANE   (H_*W_) // 12544
#define NGRP    8       // batch pairs: g owns b = {2g, 2g+1}

// ---------------------------------------------------------------------------
// Kernel 1: deterministic partial reduction, float4 streaming.
//   Spart[p][n][g] = sum over b in {2g,2g+1}, nh, nw of
//                    logits[b, n, 7*nh + p_r, 7*nw + p_c]
// One block per (n, r, g).  Lane l<56: f = l%28 owns float4 columns
// 4f..4f+3; rho = l/28 owns row parity.  8 unrolled iters x 2 planes =
// 16 aligned 16B loads/lane.  Flush is atomic-free: 224 lanes-slots write
// colsum[112][2] (exactly covered, no init), 7 threads fold cols mod 7.
// Grid = 100 * 7 * 8 = 5600 blocks x 64 threads.
// ---------------------------------------------------------------------------
__global__ __launch_bounds__(64) void reduce_kernel(const float* __restrict__ logits,
                                                    float* __restrict__ Spart) {
    int blk = blockIdx.x;          // [0, 5600)
    int g   = blk & 7;             // batch-pair
    int rn  = blk >> 3;
    int r   = rn % 7;
    int n   = rn / 7;              // point index

    const float* pl0 = logits + ((size_t)(2 * g) * NPTS + n) * PLANE;
    const float* pl1 = pl0 + (size_t)NPTS * PLANE;   // b = 2g+1

    __shared__ float colsum[112][2];

    int t = threadIdx.x;           // 0..63
    if (t < 56) {
        int f   = t % 28;          // float4 index within row (cols 4f..4f+3)
        int rho = t / 28;          // row parity

        float a0 = 0.0f, a1 = 0.0f, a2 = 0.0f, a3 = 0.0f;
        #pragma unroll
        for (int k2 = 0; k2 < 8; ++k2) {
            int row = r + 7 * (2 * k2 + rho);          // <= 6 + 7*15 = 111
            const float4* A = (const float4*)(pl0 + (size_t)row * W_) + f;
            const float4* Bq = (const float4*)(pl1 + (size_t)row * W_) + f;
            float4 x = *A;
            float4 y = *Bq;
            a0 += x.x + y.x;
            a1 += x.y + y.y;
            a2 += x.z + y.z;
            a3 += x.w + y.w;
        }
        colsum[4 * f + 0][rho] = a0;
        colsum[4 * f + 1][rho] = a1;
        colsum[4 * f + 2][rho] = a2;
        colsum[4 * f + 3][rho] = a3;
    }
    __syncthreads();

    if (t < 7) {
        // p-bin c = t: columns c, c+7, ..., c+105 (16 cols) x 2 parities
        float s = 0.0f;
        #pragma unroll
        for (int m = 0; m < 16; ++m) {
            int col = t + 7 * m;
            s += colsum[col][0] + colsum[col][1];
        }
        Spart[(r * 7 + t) * (NPTS * NGRP) + n * NGRP + g] = s;
    }
}

// ---------------------------------------------------------------------------
// Kernel 2 (FUSED weights + apply): 512 blocks x 448 threads (7 waves).
//   Phase 1a: 392 threads (49 p x 8 chunks) compute partial weighted sums
//             over the 100 points from Spart (L2/L3-resident, float4).
//   Phase 1b: 49 threads finalize params, build normalized padded 7x7 kernel
//             in LDS (static-index k5 stays in registers).
//   Phase 2 : 2401 bilinear-translate items across 448 threads -> WtT in LDS.
//   Phase 3 : wave i computes output row i for the block's 64 tiles; WtT rows
//             are read as wave-uniform float4 LDS broadcasts.
// ---------------------------------------------------------------------------
#define NTB 448

__global__ __launch_bounds__(NTB) void fused_kernel(const float* __restrict__ inp,
                                                    const float* __restrict__ Spart,
                                                    const float* __restrict__ sigx,
                                                    const float* __restrict__ sigy,
                                                    const float* __restrict__ opac,
                                                    const float* __restrict__ rho,
                                                    float* __restrict__ out) {
    __shared__ float ph1[P_][8][4];     // per-(p,chunk) partial {wsx,wsy,wop,wrho}
    __shared__ float k7n[P_][P_ + 1];   // [p][i*7+j], normalized padded kernel
    __shared__ float wopS[P_];
    __shared__ float WtT[P_ * 52];      // [q][p], row-padded to 52 (16B-aligned rows)

    int t = threadIdx.x;

    // --- phase 1a: chunk-parallel weighted sums over the 100 points ---
    if (t < 392) {
        int p = t >> 3;                 // 0..48
        int s = t & 7;                  // chunk 0..7
        int n0  = s * 12 + (s < 4 ? s : 4);   // 13,13,13,13,12,12,12,12
        int len = (s < 4) ? 13 : 12;

        float psx = 0.0f, psy = 0.0f, pop = 0.0f, prh = 0.0f;
        const float* base = Spart + p * (NPTS * NGRP);
        for (int e = 0; e < len; ++e) {
            int n = n0 + e;
            const float4* sp = (const float4*)(base + n * NGRP);
            float4 a = sp[0], b = sp[1];
            float l = (a.x + a.y + a.z + a.w + b.x + b.y + b.z + b.w)
                      * (1.0f / 4096.0f);       // mean over 16*16*16 patches
            psx += l * sigx[n];
            psy += l * sigy[n];
            pop += l * opac[n];
            prh += l * rho[n];
        }
        ph1[p][s][0] = psx; ph1[p][s][1] = psy;
        ph1[p][s][2] = pop; ph1[p][s][3] = prh;
    }
    __syncthreads();

    // --- phase 1b: finalize per-p params + normalized padded kernel ---
    if (t < P_) {
        float wsx = 0.0f, wsy = 0.0f, wop = 0.0f, wrho = 0.0f;
        #pragma unroll
        for (int s = 0; s < 8; ++s) {
            wsx  += ph1[t][s][0];
            wsy  += ph1[t][s][1];
            wop  += ph1[t][s][2];
            wrho += ph1[t][s][3];
        }
        wopS[t] = wop;

        float a   = wsx * wsx + 1e-5f;
        float d   = wsy * wsy + 1e-5f;
        float b   = wrho * wsx * wsy;
        float det = a * d - b * b;
        float ia  = d / det, ib = -b / det, idd = a / det;

        // 5x5 gaussian on linspace(-5,5,5); 1/(2*pi*sqrt(det)) cancels under
        // max-normalization.  Static indexing only -> stays in registers.
        float k5[25];
        float kmax = -1e30f;
        #pragma unroll
        for (int i = 0; i < 5; ++i) {
            float x = -5.0f + 2.5f * (float)i;
            #pragma unroll
            for (int j = 0; j < 5; ++j) {
                float y = -5.0f + 2.5f * (float)j;
                float z = -0.5f * (ia * x * x + 2.0f * ib * x * y + idd * y * y);
                float v = expf(z);
                k5[i * 5 + j] = v;
                kmax = fmaxf(kmax, v);
            }
        }
        float inv = 1.0f / kmax;

        // padded 7x7 (1-px zero border) straight into LDS
        #pragma unroll
        for (int q = 0; q < P_; ++q) k7n[t][q] = 0.0f;
        #pragma unroll
        for (int i = 0; i < 5; ++i)
            #pragma unroll
            for (int j = 0; j < 5; ++j)
                k7n[t][(i + 1) * 7 + (j + 1)] = k5[i * 5 + j] * inv;
    }
    __syncthreads();

    // --- phase 2: bilinear translate, (p,q) items -> WtT[q][p] in LDS ---
    for (int idx = t; idx < P_ * P_; idx += NTB) {
        int p = idx / P_;
        int q = idx - p * P_;
        int i = q / 7, j = q % 7;
        int r = p / 7, c = p % 7;

        float sx = 3.0f - (6.0f / 7.0f) * (float)c;   // tx*(COL-1)/2
        float sy = 3.0f - (6.0f / 7.0f) * (float)r;   // ty*(ROW-1)/2

        float ii  = (float)i + sy;
        float jj  = (float)j + sx;
        float fi0 = floorf(ii), fj0 = floorf(jj);
        int   i0  = (int)fi0,   j0  = (int)fj0;
        float wi  = ii - fi0,   wj  = jj - fj0;

        bool iv0 = (i0 >= 0)     && (i0 <= 6);
        bool iv1 = (i0 + 1 >= 0) && (i0 + 1 <= 6);
        bool jv0 = (j0 >= 0)     && (j0 <= 6);
        bool jv1 = (j0 + 1 >= 0) && (j0 + 1 <= 6);
        int ci0 = min(max(i0, 0), 6),     cj0 = min(max(j0, 0), 6);
        int ci1 = min(max(i0 + 1, 0), 6), cj1 = min(max(j0 + 1, 0), 6);

        float v00 = (iv0 && jv0) ? k7n[p][ci0 * 7 + cj0] : 0.0f;
        float v01 = (iv0 && jv1) ? k7n[p][ci0 * 7 + cj1] : 0.0f;
        float v10 = (iv1 && jv0) ? k7n[p][ci1 * 7 + cj0] : 0.0f;
        float v11 = (iv1 && jv1) ? k7n[p][ci1 * 7 + cj1] : 0.0f;

        float kt = v00 * (1.0f - wi) * (1.0f - wj)
                 + v01 * (1.0f - wi) * wj
                 + v10 * wi * (1.0f - wj)
                 + v11 * wi * wj;

        WtT[q * 52 + p] = wopS[p] * kt;
    }
    __syncthreads();

    // --- phase 3: apply.  wave i handles output row i for 64 tiles. ---
    int lane = t & 63;
    int i    = t >> 6;                       // 0..6 = output row within tile
    int bl   = blockIdx.x * 64 + lane;       // tile id [0, 32768)
    int nw = bl & 15;
    int u  = bl >> 4;
    int nh = u & 15;
    u >>= 4;
    int ch    = u & 7;
    int batch = u >> 3;

    const float* src = inp + (((size_t)batch * C_IN    + ch) * H_ + nh * 7) * W_ + nw * 7;
    float*       dst = out + (((size_t)batch * FEAT_C_ + ch) * H_ + nh * 7) * W_ + nw * 7;

    float in[P_];
    #pragma unroll
    for (int r = 0; r < 7; ++r)
        #pragma unroll
        for (int c = 0; c < 7; ++c)
            in[r * 7 + c] = src[r * W_ + c];

    #pragma unroll
    for (int j = 0; j < 7; ++j) {
        const float* w = &WtT[(i * 7 + j) * 52];   // wave-uniform LDS row, 16B-aligned
        float a0 = 0.0f, a1 = 0.0f, a2 = 0.0f, a3 = 0.0f;
        #pragma unroll
        for (int p4 = 0; p4 < 12; ++p4) {
            a0 += in[p4 * 4 + 0] * w[p4 * 4 + 0];
            a1 += in[p4 * 4 + 1] * w[p4 * 4 + 1];
            a2 += in[p4 * 4 + 2] * w[p4 * 4 + 2];
            a3 += in[p4 * 4 + 3] * w[p4 * 4 + 3];
        }
        float acc = ((a0 + a2) + (a1 + a3)) + in[48] * w[48];
        dst[i * W_ + j] = acc;
    }
}

// ---------------------------------------------------------------------------
extern "C" void kernel_launch(void* const* d_in, const int* in_sizes, int n_in,
                              void* d_out, int out_size, void* d_ws, size_t ws_size,
                              hipStream_t stream) {
    const float* inp    = (const float*)d_in[0];  // (16, 64, 112, 112)
    const float* logits = (const float*)d_in[1];  // (16, 100, 112, 112)
    const float* sigx   = (const float*)d_in[2];  // (100,)
    const float* sigy   = (const float*)d_in[3];  // (100,)
    const float* opac   = (const float*)d_in[4];  // (100,1) flat
    const float* rho    = (const float*)d_in[5];  // (100,1) flat
    // d_in[6] = scale (unused by reference)

    float* out   = (float*)d_out;                 // (16, 8, 112, 112) f32
    float* Spart = (float*)d_ws;                  // 49*100*8 floats (157 KB)

    reduce_kernel<<<NPTS * 7 * NGRP, 64, 0, stream>>>(logits, Spart);
    fused_kernel<<<(B_ * FEAT_C_ * NH_ * NW_) / 64, NTB, 0, stream>>>(
        inp, Spart, sigx, sigy, opac, rho, out);
}